// Round 2
// baseline (5876.554 us; speedup 1.0000x reference)
//
#include <hip/hip_runtime.h>
#include <cstring>
#include <cstdio>

typedef __attribute__((ext_vector_type(8))) short short8;
typedef __attribute__((ext_vector_type(4))) float f32x4;

__device__ __forceinline__ short f2bf(float f){
  unsigned u; __builtin_memcpy(&u, &f, 4);
  u += 0x7FFFu + ((u >> 16) & 1u);
  return (short)(u >> 16);
}
__device__ __forceinline__ float bf2f(short s){
  unsigned u = ((unsigned)(unsigned short)s) << 16;
  float f; __builtin_memcpy(&f, &u, 4);
  return f;
}
__device__ __forceinline__ void split2(float v, short& hi, short& lo){
  hi = f2bf(v);
  float r = v - bf2f(hi);   // exact (Sterbenz)
  lo = f2bf(r);
}
__device__ __forceinline__ float tanh_fast(float x){
  float e = __expf(2.0f * x);
  return 1.0f - 2.0f / (e + 1.0f);
}

// ---------------------------------------------------------------------------
// K0a: transpose + hi/lo split: outh[c][r] + outl[c][r] = split(in[r][c])
// ---------------------------------------------------------------------------
__global__ void transpose_split(const float* __restrict__ in,
                                short* __restrict__ outh, short* __restrict__ outl,
                                int R, int C){
  int idx = blockIdx.x * 256 + threadIdx.x;
  if (idx < R * C){
    int r = idx / C, c = idx % C;
    short h, l; split2(in[(size_t)r * C + c], h, l);
    outh[(size_t)c * R + r] = h;
    outl[(size_t)c * R + r] = l;
  }
}

// K0b: plain transpose to single bf16 (for Wout)
__global__ void transpose_to_bf16(const float* __restrict__ in, short* __restrict__ out,
                                  int R, int C){
  int idx = blockIdx.x * 256 + threadIdx.x;
  if (idx < R * C){
    int r = idx / C, c = idx % C;
    out[(size_t)c * R + r] = f2bf(in[(size_t)r * C + c]);
  }
}

// ---------------------------------------------------------------------------
// K1: x [B=256][D=256][T=256] f32 -> xT_hi/xT_lo [(t*256+b)][d] bf16
// ---------------------------------------------------------------------------
__global__ __launch_bounds__(256) void transpose_x_split(const float* __restrict__ x,
                                                         short* __restrict__ xTh,
                                                         short* __restrict__ xTl){
  __shared__ float tile[64][65];
  const int b = blockIdx.x, d0 = blockIdx.y * 64, t0 = blockIdx.z * 64;
  const int tid = threadIdx.x;
  const float* xp = x + ((size_t)b * 256 + d0) * 256 + t0;
  for (int v = tid; v < 1024; v += 256){
    int r = v >> 4, c4 = (v & 15) * 4;
    float4 f = *(const float4*)(xp + (size_t)r * 256 + c4);
    tile[r][c4+0] = f.x; tile[r][c4+1] = f.y; tile[r][c4+2] = f.z; tile[r][c4+3] = f.w;
  }
  __syncthreads();
  for (int v = tid; v < 512; v += 256){
    int j = v >> 3, i8 = (v & 7) * 8;
    short8 oh, ol;
    #pragma unroll
    for (int u = 0; u < 8; ++u){ short h, l; split2(tile[i8 + u][j], h, l); oh[u] = h; ol[u] = l; }
    size_t off = ((size_t)(t0 + j) * 256 + b) * 256 + d0 + i8;
    *(short8*)(xTh + off) = oh;
    *(short8*)(xTl + off) = ol;
  }
}

// ---------------------------------------------------------------------------
// K2: split-precision GEMM (3-product): C = (Ah+Al)@(Bh+Bl)^T + bias, fp32 out.
// M=65536, N=512, K=256. Output rows < 32768 -> C0, else C1 (row-32768).
// 64x64 tile, 4 waves (2x2), 16x16x32 bf16 MFMA.
// ---------------------------------------------------------------------------
__global__ __launch_bounds__(256) void gemm1_split(
    const short* __restrict__ Ah, const short* __restrict__ Al,
    const short* __restrict__ Bh, const short* __restrict__ Bl,
    const float* __restrict__ bias, float* __restrict__ C0, float* __restrict__ C1,
    int M, int N, int K)
{
  __shared__ short lAh[64][72];
  __shared__ short lAl[64][72];
  __shared__ short lBh[64][72];
  __shared__ short lBl[64][72];
  const int m0 = blockIdx.y * 64, n0 = blockIdx.x * 64;
  const int tid = threadIdx.x;
  const int lane = tid & 63, wave = tid >> 6;
  const int wm = (wave >> 1) * 32, wn = (wave & 1) * 32;
  f32x4 acc[2][2] = {};
  for (int k0 = 0; k0 < K; k0 += 64){
    __syncthreads();
    for (int v = tid; v < 2048; v += 256){
      int sel = v >> 9, idx = v & 511;
      int r = idx >> 3, c = (idx & 7) * 8;
      const short* src = (sel == 0) ? Ah + (size_t)(m0 + r) * K + k0 + c
                       : (sel == 1) ? Al + (size_t)(m0 + r) * K + k0 + c
                       : (sel == 2) ? Bh + (size_t)(n0 + r) * K + k0 + c
                                    : Bl + (size_t)(n0 + r) * K + k0 + c;
      short8 val = *(const short8*)src;
      short* dst = (sel == 0) ? &lAh[r][c] : (sel == 1) ? &lAl[r][c]
                 : (sel == 2) ? &lBh[r][c] : &lBl[r][c];
      *(short8*)dst = val;
    }
    __syncthreads();
    #pragma unroll
    for (int kk = 0; kk < 64; kk += 32){
      int ko = kk + (lane >> 4) * 8;
      short8 ah0 = *(const short8*)&lAh[wm +      (lane & 15)][ko];
      short8 ah1 = *(const short8*)&lAh[wm + 16 + (lane & 15)][ko];
      short8 al0 = *(const short8*)&lAl[wm +      (lane & 15)][ko];
      short8 al1 = *(const short8*)&lAl[wm + 16 + (lane & 15)][ko];
      short8 bh0 = *(const short8*)&lBh[wn +      (lane & 15)][ko];
      short8 bh1 = *(const short8*)&lBh[wn + 16 + (lane & 15)][ko];
      short8 bl0 = *(const short8*)&lBl[wn +      (lane & 15)][ko];
      short8 bl1 = *(const short8*)&lBl[wn + 16 + (lane & 15)][ko];
      acc[0][0] = __builtin_amdgcn_mfma_f32_16x16x32_bf16(ah0, bh0, acc[0][0], 0, 0, 0);
      acc[0][1] = __builtin_amdgcn_mfma_f32_16x16x32_bf16(ah0, bh1, acc[0][1], 0, 0, 0);
      acc[1][0] = __builtin_amdgcn_mfma_f32_16x16x32_bf16(ah1, bh0, acc[1][0], 0, 0, 0);
      acc[1][1] = __builtin_amdgcn_mfma_f32_16x16x32_bf16(ah1, bh1, acc[1][1], 0, 0, 0);
      acc[0][0] = __builtin_amdgcn_mfma_f32_16x16x32_bf16(ah0, bl0, acc[0][0], 0, 0, 0);
      acc[0][1] = __builtin_amdgcn_mfma_f32_16x16x32_bf16(ah0, bl1, acc[0][1], 0, 0, 0);
      acc[1][0] = __builtin_amdgcn_mfma_f32_16x16x32_bf16(ah1, bl0, acc[1][0], 0, 0, 0);
      acc[1][1] = __builtin_amdgcn_mfma_f32_16x16x32_bf16(ah1, bl1, acc[1][1], 0, 0, 0);
      acc[0][0] = __builtin_amdgcn_mfma_f32_16x16x32_bf16(al0, bh0, acc[0][0], 0, 0, 0);
      acc[0][1] = __builtin_amdgcn_mfma_f32_16x16x32_bf16(al0, bh1, acc[0][1], 0, 0, 0);
      acc[1][0] = __builtin_amdgcn_mfma_f32_16x16x32_bf16(al1, bh0, acc[1][0], 0, 0, 0);
      acc[1][1] = __builtin_amdgcn_mfma_f32_16x16x32_bf16(al1, bh1, acc[1][1], 0, 0, 0);
    }
  }
  const int cr = (lane >> 4) * 4, cc = lane & 15;
  #pragma unroll
  for (int i = 0; i < 2; ++i)
  #pragma unroll
  for (int j = 0; j < 2; ++j){
    int row = m0 + wm + i * 16 + cr;
    int col = n0 + wn + j * 16 + cc;
    float bv = bias[col];
    float* base = (row < 32768) ? C0 : C1;
    int rr = (row < 32768) ? row : row - 32768;
    #pragma unroll
    for (int r = 0; r < 4; ++r){
      base[(size_t)(rr + r) * N + col] = acc[i][j][r] + bv;
    }
  }
}

// ---------------------------------------------------------------------------
// K3: persistent recurrence, split-precision (3-product) h@Wh.
// 32 blocks x 256 threads; block owns 8 batch rows. h master fp32 in LDS,
// hi/lo bf16 copies for MFMA A-frags. WhT_hi/lo streamed from L2 as B-frags.
// xproj read fp32 (part0/part1). states written single bf16.
// ---------------------------------------------------------------------------
__global__ __launch_bounds__(256) void rnn_steps_split(
    const float* __restrict__ xp0,    // [t<128]  [(t*256+b)][512] f32
    const float* __restrict__ xp1,    // [t>=128] [((t-128)*256+b)][512] f32
    const short* __restrict__ WhTh,   // [512][512] bf16 hi, [n][k]
    const short* __restrict__ WhTl,   // [512][512] bf16 lo
    const float* __restrict__ init,   // [512]
    short* __restrict__ states)       // [(b*256+t)][512] bf16
{
  __shared__ float hs[8][512];
  __shared__ short hbh[8][520];
  __shared__ short hbl[8][520];
  const int tid = threadIdx.x, lane = tid & 63, wave = tid >> 6;
  const int b0 = blockIdx.x * 8;
  const int nw = wave * 128;

  for (int v = tid; v < 8 * 512; v += 256){
    int m = v >> 9, n = v & 511;
    float h = init[n];
    hs[m][n] = h;
    short hi, lo; split2(h, hi, lo);
    hbh[m][n] = hi; hbl[m][n] = lo;
  }
  __syncthreads();

  const int cc = lane & 15;
  const bool islo = (lane < 32);
  const int mbase = ((lane & 31) >> 4) * 4;
  const int m_0 = mbase + (islo ? 0 : 2);
  const int m_1 = mbase + (islo ? 1 : 3);
  const int am = lane & 15;               // A-frag row for this lane

  for (int t = 0; t < 256; ++t){
    f32x4 acc[8] = {};
    for (int ks = 0; ks < 16; ++ks){
      int ko = ks * 32 + (lane >> 4) * 8;
      short8 afh = {}, afl = {};
      if (am < 8){
        afh = *(const short8*)&hbh[am][ko];
        afl = *(const short8*)&hbl[am][ko];
      }
      #pragma unroll
      for (int nf = 0; nf < 8; ++nf){
        int n = nw + nf * 16 + (lane & 15);
        short8 bh = *(const short8*)(WhTh + (size_t)n * 512 + ko);
        short8 bl = *(const short8*)(WhTl + (size_t)n * 512 + ko);
        acc[nf] = __builtin_amdgcn_mfma_f32_16x16x32_bf16(afh, bh, acc[nf], 0, 0, 0);
        acc[nf] = __builtin_amdgcn_mfma_f32_16x16x32_bf16(afh, bl, acc[nf], 0, 0, 0);
        acc[nf] = __builtin_amdgcn_mfma_f32_16x16x32_bf16(afl, bh, acc[nf], 0, 0, 0);
      }
    }
    const float* xpb = (t < 128) ? xp0 : xp1;
    const int tt = (t < 128) ? t : t - 128;
    #pragma unroll
    for (int nf = 0; nf < 8; ++nf){
      int n = nw + nf * 16 + cc;
      float s2 = __shfl(acc[nf][2], lane ^ 32);
      float s3 = __shfl(acc[nf][3], lane ^ 32);
      float v0 = islo ? acc[nf][0] : s2;
      float v1 = islo ? acc[nf][1] : s3;
      float xpv0 = xpb[((size_t)tt * 256 + b0 + m_0) * 512 + n];
      float xpv1 = xpb[((size_t)tt * 256 + b0 + m_1) * 512 + n];
      float h0 = hs[m_0][n], h1 = hs[m_1][n];
      float hn0 = tanh_fast(xpv0 + v0) + h0;
      float hn1 = tanh_fast(xpv1 + v1) + h1;
      hs[m_0][n] = hn0;
      hs[m_1][n] = hn1;
      states[((size_t)(b0 + m_0) * 256 + t) * 512 + n] = f2bf(hn0);
      states[((size_t)(b0 + m_1) * 256 + t) * 512 + n] = f2bf(hn1);
    }
    __syncthreads();
    for (int v = tid; v < 8 * 512; v += 256){
      int m = v >> 9, n = v & 511;
      short hi, lo; split2(hs[m][n], hi, lo);
      hbh[m][n] = hi; hbl[m][n] = lo;
    }
    __syncthreads();
  }
}

// ---------------------------------------------------------------------------
// K4: single-precision bf16 GEMM for the output projection.
// A [M][K] bf16, Bt [N][K] bf16, C fp32 [M][N] = A*B + bias.
// ---------------------------------------------------------------------------
__global__ __launch_bounds__(256) void gemm_bias_f32(
    const short* __restrict__ A, const short* __restrict__ Bt,
    const float* __restrict__ bias, float* __restrict__ C,
    int M, int N, int K)
{
  __shared__ short lA[64][72];
  __shared__ short lB[64][72];
  const int m0 = blockIdx.y * 64, n0 = blockIdx.x * 64;
  const int tid = threadIdx.x;
  const int lane = tid & 63, wave = tid >> 6;
  const int wm = (wave >> 1) * 32, wn = (wave & 1) * 32;
  f32x4 acc[2][2] = {};
  for (int k0 = 0; k0 < K; k0 += 64){
    __syncthreads();
    for (int v = tid; v < 512; v += 256){
      int r = v >> 3, c = v & 7;
      *(short8*)&lA[r][c*8] = *(const short8*)(A + (size_t)(m0 + r) * K + k0 + c*8);
      *(short8*)&lB[r][c*8] = *(const short8*)(Bt + (size_t)(n0 + r) * K + k0 + c*8);
    }
    __syncthreads();
    #pragma unroll
    for (int kk = 0; kk < 64; kk += 32){
      int ko = kk + (lane >> 4) * 8;
      short8 a0 = *(const short8*)&lA[wm +      (lane & 15)][ko];
      short8 a1 = *(const short8*)&lA[wm + 16 + (lane & 15)][ko];
      short8 b0 = *(const short8*)&lB[wn +      (lane & 15)][ko];
      short8 b1 = *(const short8*)&lB[wn + 16 + (lane & 15)][ko];
      acc[0][0] = __builtin_amdgcn_mfma_f32_16x16x32_bf16(a0, b0, acc[0][0], 0, 0, 0);
      acc[0][1] = __builtin_amdgcn_mfma_f32_16x16x32_bf16(a0, b1, acc[0][1], 0, 0, 0);
      acc[1][0] = __builtin_amdgcn_mfma_f32_16x16x32_bf16(a1, b0, acc[1][0], 0, 0, 0);
      acc[1][1] = __builtin_amdgcn_mfma_f32_16x16x32_bf16(a1, b1, acc[1][1], 0, 0, 0);
    }
  }
  const int cr = (lane >> 4) * 4, cc = lane & 15;
  #pragma unroll
  for (int i = 0; i < 2; ++i)
  #pragma unroll
  for (int j = 0; j < 2; ++j){
    int row = m0 + wm + i * 16 + cr;
    int col = n0 + wn + j * 16 + cc;
    float bv = bias[col];
    #pragma unroll
    for (int r = 0; r < 4; ++r){
      C[(size_t)(row + r) * N + col] = acc[i][j][r] + bv;
    }
  }
}

// ---------------------------------------------------------------------------
extern "C" void kernel_launch(void* const* d_in, const int* in_sizes, int n_in,
                              void* d_out, int out_size, void* d_ws, size_t ws_size,
                              hipStream_t stream){
  (void)in_sizes; (void)n_in; (void)out_size;
  const float* x    = (const float*)d_in[0];
  const float* Wx   = (const float*)d_in[1];
  const float* Wh   = (const float*)d_in[2];
  const float* bias = (const float*)d_in[3];
  const float* Wout = (const float*)d_in[4];
  const float* bout = (const float*)d_in[5];
  const float* init = (const float*)d_in[6];
  float* out = (float*)d_out;

  char* p = (char*)d_ws;
  // Region [0, 64Mi): xT_hi (32Mi) + xT_lo (32Mi) during GEMM1; then states (64Mi).
  short* xTh    = (short*)(p);
  short* xTl    = (short*)(p + 33554432);
  short* states = (short*)(p);
  // xproj fp32: rows [0,32768) in ws, rows [32768,65536) in d_out (dead until GEMM2).
  float* xproj0 = (float*)(p + 67108864);     // 64 MiB
  float* xproj1 = (float*)d_out;              // 64 MiB
  short* WxTh   = (short*)(p + 134217728);    // 256 KiB
  short* WxTl   = (short*)(p + 134479872);    // 256 KiB
  short* WhTh   = (short*)(p + 134742016);    // 512 KiB
  short* WhTl   = (short*)(p + 135266304);    // 512 KiB
  short* WoutT  = (short*)(p + 135790592);    // 256 KiB
  if (ws_size < 136052736u){
    fprintf(stderr, "kernel_launch: ws_size=%zu < 136052736 needed\n", ws_size);
  }

  transpose_split<<<(256*512 + 255)/256, 256, 0, stream>>>(Wx, WxTh, WxTl, 256, 512);
  transpose_split<<<(512*512 + 255)/256, 256, 0, stream>>>(Wh, WhTh, WhTl, 512, 512);
  transpose_to_bf16<<<(512*256 + 255)/256, 256, 0, stream>>>(Wout, WoutT, 512, 256);
  transpose_x_split<<<dim3(256, 4, 4), 256, 0, stream>>>(x, xTh, xTl);
  // xproj = (xT)@(Wx) + b at ~fp32 precision (3-product split MFMA)
  gemm1_split<<<dim3(8, 1024), 256, 0, stream>>>(xTh, xTl, WxTh, WxTl, bias,
                                                 xproj0, xproj1, 65536, 512, 256);
  // recurrence (3-product split)
  rnn_steps_split<<<32, 256, 0, stream>>>(xproj0, xproj1, WhTh, WhTl, init, states);
  // out = states @ Wout + bout  (single bf16 product)
  gemm_bias_f32<<<dim3(4, 1024), 256, 0, stream>>>(states, WoutT, bout, out, 65536, 256, 512);
}

// Round 3
// 2538.251 us; speedup vs baseline: 2.3152x; 2.3152x over previous
//
#include <hip/hip_runtime.h>
#include <cstring>
#include <cstdio>

typedef __attribute__((ext_vector_type(8))) short short8;
typedef __attribute__((ext_vector_type(4))) float f32x4;

__device__ __forceinline__ short f2bf(float f){
  unsigned u; __builtin_memcpy(&u, &f, 4);
  u += 0x7FFFu + ((u >> 16) & 1u);
  return (short)(u >> 16);
}
__device__ __forceinline__ float bf2f(short s){
  unsigned u = ((unsigned)(unsigned short)s) << 16;
  float f; __builtin_memcpy(&f, &u, 4);
  return f;
}
__device__ __forceinline__ void split2(float v, short& hi, short& lo){
  hi = f2bf(v);
  float r = v - bf2f(hi);   // exact (Sterbenz)
  lo = f2bf(r);
}
__device__ __forceinline__ unsigned pack2(float v){
  short hi, lo; split2(v, hi, lo);
  return (((unsigned)(unsigned short)hi) << 16) | (unsigned)(unsigned short)lo;
}
__device__ __forceinline__ float tanh_fast(float x){
  float e = __expf(2.0f * x);
  return 1.0f - 2.0f / (e + 1.0f);
}

// swizzled LDS short-index for h planes: element (r,k) -> idx, XOR bits 3..5
#define HIDX(r,k) ((((r) * 512) + (k)) ^ (((r) & 7) << 3))

// ---------------------------------------------------------------------------
// K0a: transpose + hi/lo split: outh[c][r] + outl[c][r] = split(in[r][c])
// ---------------------------------------------------------------------------
__global__ void transpose_split(const float* __restrict__ in,
                                short* __restrict__ outh, short* __restrict__ outl,
                                int R, int C){
  int idx = blockIdx.x * 256 + threadIdx.x;
  if (idx < R * C){
    int r = idx / C, c = idx % C;
    short h, l; split2(in[(size_t)r * C + c], h, l);
    outh[(size_t)c * R + r] = h;
    outl[(size_t)c * R + r] = l;
  }
}

// K0b: plain transpose to single bf16 (for Wout)
__global__ void transpose_to_bf16(const float* __restrict__ in, short* __restrict__ out,
                                  int R, int C){
  int idx = blockIdx.x * 256 + threadIdx.x;
  if (idx < R * C){
    int r = idx / C, c = idx % C;
    out[(size_t)c * R + r] = f2bf(in[(size_t)r * C + c]);
  }
}

// ---------------------------------------------------------------------------
// K1: x [B=256][D=256][T=256] f32 -> xT_hi/xT_lo [(t*256+b)][d] bf16
// ---------------------------------------------------------------------------
__global__ __launch_bounds__(256) void transpose_x_split(const float* __restrict__ x,
                                                         short* __restrict__ xTh,
                                                         short* __restrict__ xTl){
  __shared__ float tile[64][65];
  const int b = blockIdx.x, d0 = blockIdx.y * 64, t0 = blockIdx.z * 64;
  const int tid = threadIdx.x;
  const float* xp = x + ((size_t)b * 256 + d0) * 256 + t0;
  for (int v = tid; v < 1024; v += 256){
    int r = v >> 4, c4 = (v & 15) * 4;
    float4 f = *(const float4*)(xp + (size_t)r * 256 + c4);
    tile[r][c4+0] = f.x; tile[r][c4+1] = f.y; tile[r][c4+2] = f.z; tile[r][c4+3] = f.w;
  }
  __syncthreads();
  for (int v = tid; v < 512; v += 256){
    int j = v >> 3, i8 = (v & 7) * 8;
    short8 oh, ol;
    #pragma unroll
    for (int u = 0; u < 8; ++u){ short h, l; split2(tile[i8 + u][j], h, l); oh[u] = h; ol[u] = l; }
    size_t off = ((size_t)(t0 + j) * 256 + b) * 256 + d0 + i8;
    *(short8*)(xTh + off) = oh;
    *(short8*)(xTl + off) = ol;
  }
}

// ---------------------------------------------------------------------------
// K2: split-precision GEMM (3-product): C = (Ah+Al)@(Bh+Bl)^T + bias, fp32 out.
// Output rows < 32768 -> C0, else C1 (row-32768).
// ---------------------------------------------------------------------------
__global__ __launch_bounds__(256) void gemm1_split(
    const short* __restrict__ Ah, const short* __restrict__ Al,
    const short* __restrict__ Bh, const short* __restrict__ Bl,
    const float* __restrict__ bias, float* __restrict__ C0, float* __restrict__ C1,
    int M, int N, int K)
{
  __shared__ short lAh[64][72];
  __shared__ short lAl[64][72];
  __shared__ short lBh[64][72];
  __shared__ short lBl[64][72];
  const int m0 = blockIdx.y * 64, n0 = blockIdx.x * 64;
  const int tid = threadIdx.x;
  const int lane = tid & 63, wave = tid >> 6;
  const int wm = (wave >> 1) * 32, wn = (wave & 1) * 32;
  f32x4 acc[2][2] = {};
  for (int k0 = 0; k0 < K; k0 += 64){
    __syncthreads();
    for (int v = tid; v < 2048; v += 256){
      int sel = v >> 9, idx = v & 511;
      int r = idx >> 3, c = (idx & 7) * 8;
      const short* src = (sel == 0) ? Ah + (size_t)(m0 + r) * K + k0 + c
                       : (sel == 1) ? Al + (size_t)(m0 + r) * K + k0 + c
                       : (sel == 2) ? Bh + (size_t)(n0 + r) * K + k0 + c
                                    : Bl + (size_t)(n0 + r) * K + k0 + c;
      short8 val = *(const short8*)src;
      short* dst = (sel == 0) ? &lAh[r][c] : (sel == 1) ? &lAl[r][c]
                 : (sel == 2) ? &lBh[r][c] : &lBl[r][c];
      *(short8*)dst = val;
    }
    __syncthreads();
    #pragma unroll
    for (int kk = 0; kk < 64; kk += 32){
      int ko = kk + (lane >> 4) * 8;
      short8 ah0 = *(const short8*)&lAh[wm +      (lane & 15)][ko];
      short8 ah1 = *(const short8*)&lAh[wm + 16 + (lane & 15)][ko];
      short8 al0 = *(const short8*)&lAl[wm +      (lane & 15)][ko];
      short8 al1 = *(const short8*)&lAl[wm + 16 + (lane & 15)][ko];
      short8 bh0 = *(const short8*)&lBh[wn +      (lane & 15)][ko];
      short8 bh1 = *(const short8*)&lBh[wn + 16 + (lane & 15)][ko];
      short8 bl0 = *(const short8*)&lBl[wn +      (lane & 15)][ko];
      short8 bl1 = *(const short8*)&lBl[wn + 16 + (lane & 15)][ko];
      acc[0][0] = __builtin_amdgcn_mfma_f32_16x16x32_bf16(ah0, bh0, acc[0][0], 0, 0, 0);
      acc[0][1] = __builtin_amdgcn_mfma_f32_16x16x32_bf16(ah0, bh1, acc[0][1], 0, 0, 0);
      acc[1][0] = __builtin_amdgcn_mfma_f32_16x16x32_bf16(ah1, bh0, acc[1][0], 0, 0, 0);
      acc[1][1] = __builtin_amdgcn_mfma_f32_16x16x32_bf16(ah1, bh1, acc[1][1], 0, 0, 0);
      acc[0][0] = __builtin_amdgcn_mfma_f32_16x16x32_bf16(ah0, bl0, acc[0][0], 0, 0, 0);
      acc[0][1] = __builtin_amdgcn_mfma_f32_16x16x32_bf16(ah0, bl1, acc[0][1], 0, 0, 0);
      acc[1][0] = __builtin_amdgcn_mfma_f32_16x16x32_bf16(ah1, bl0, acc[1][0], 0, 0, 0);
      acc[1][1] = __builtin_amdgcn_mfma_f32_16x16x32_bf16(ah1, bl1, acc[1][1], 0, 0, 0);
      acc[0][0] = __builtin_amdgcn_mfma_f32_16x16x32_bf16(al0, bh0, acc[0][0], 0, 0, 0);
      acc[0][1] = __builtin_amdgcn_mfma_f32_16x16x32_bf16(al0, bh1, acc[0][1], 0, 0, 0);
      acc[1][0] = __builtin_amdgcn_mfma_f32_16x16x32_bf16(al1, bh0, acc[1][0], 0, 0, 0);
      acc[1][1] = __builtin_amdgcn_mfma_f32_16x16x32_bf16(al1, bh1, acc[1][1], 0, 0, 0);
    }
  }
  const int cr = (lane >> 4) * 4, cc = lane & 15;
  #pragma unroll
  for (int i = 0; i < 2; ++i)
  #pragma unroll
  for (int j = 0; j < 2; ++j){
    int row = m0 + wm + i * 16 + cr;
    int col = n0 + wn + j * 16 + cc;
    float bv = bias[col];
    float* base = (row < 32768) ? C0 : C1;
    int rr = (row < 32768) ? row : row - 32768;
    #pragma unroll
    for (int r = 0; r < 4; ++r){
      base[(size_t)(rr + r) * N + col] = acc[i][j][r] + bv;
    }
  }
}

// ---------------------------------------------------------------------------
// K3 v3: team-parallel recurrence across 256 CUs.
// 256 blocks = 32 teams (8 batch rows) x 8 N-slices (64 cols). 4 waves/block,
// wave owns 16 cols; its Wh slice (hi+lo) lives in 128 VGPRs for all 256 steps.
// h exchanged per step via packed (bf16hi|bf16lo) uint32 buffer with
// agent-scope atomics + per-team release/acquire counter. LDS h is XOR-swizzled.
// ---------------------------------------------------------------------------
__global__ __launch_bounds__(256, 2) void rnn_steps_v3(
    const float* __restrict__ xp0,    // t<128:  [(t*256+b)][512] f32
    const float* __restrict__ xp1,    // t>=128: [((t-128)*256+b)][512] f32
    const short* __restrict__ WhTh,   // [512][512] bf16 hi, [n][k]
    const short* __restrict__ WhTl,   // [512][512] bf16 lo
    const float* __restrict__ init,   // [512]
    short* __restrict__ states,       // [(b*256+t)][512] bf16
    unsigned* __restrict__ ex,        // [2][32][8][512] packed hi|lo
    unsigned* __restrict__ cnt)       // [32] counters, stride 32 uints (128B)
{
  __shared__ short hh[16 * 512];      // h hi plane, swizzled, rows 8..15 zero
  __shared__ short hl[16 * 512];      // h lo plane
  const int tid = threadIdx.x, lane = tid & 63, wave = tid >> 6;
  const int team = blockIdx.x & 31, slice = blockIdx.x >> 5;
  const int b0 = team * 8;
  const int nc = slice * 64 + wave * 16;          // this wave's global col base

  // ---- prologue: Wh B-fragments into registers (hi+lo, 16 k-steps) ----
  short8 Bh[16], Bl[16];
  {
    const size_t col = (size_t)(nc + (lane & 15));
    const int kb = (lane >> 4) * 8;
    #pragma unroll
    for (int ks = 0; ks < 16; ++ks){
      Bh[ks] = *(const short8*)(WhTh + col * 512 + ks * 32 + kb);
      Bl[ks] = *(const short8*)(WhTl + col * 512 + ks * 32 + kb);
    }
  }
  // zero pad rows 8..15 once; fill rows 0..7 with init
  for (int v = tid; v < 8 * 512; v += 256){
    int r = 8 + (v >> 9), k = v & 511;
    hh[HIDX(r, k)] = 0; hl[HIDX(r, k)] = 0;
  }
  for (int v = tid; v < 8 * 512; v += 256){
    int r = v >> 9, k = v & 511;
    short hi, lo; split2(init[k], hi, lo);
    hh[HIDX(r, k)] = hi; hl[HIDX(r, k)] = lo;
  }
  __syncthreads();

  // ---- per-lane epilogue constants (same mapping as verified r2 kernel) ----
  const int cc = lane & 15;
  const bool islo = (lane < 32);
  const int mbase = ((lane & 31) >> 4) * 4;
  const int m_0 = mbase + (islo ? 0 : 2);
  const int m_1 = mbase + (islo ? 1 : 3);
  const int n = nc + cc;                           // global col of this lane
  float hr0 = init[n], hr1 = init[n];              // fp32 residual masters

  const int am = lane & 15, kb = (lane >> 4) * 8;
  const int rr = tid >> 5, c0 = (tid & 31) * 16;   // exchange-read assignment

  for (int t = 0; t < 256; ++t){
    if (t > 0){
      // gate: wait until all 8 team blocks posted step t
      if (tid == 0){
        const unsigned target = (unsigned)(8 * t);
        while (__hip_atomic_load(cnt + team * 32, __ATOMIC_ACQUIRE,
                                 __HIP_MEMORY_SCOPE_AGENT) < target)
          __builtin_amdgcn_s_sleep(2);
      }
      __syncthreads();
      // read full h_t (packed) from exchange buf[t&1], unpack into LDS
      const unsigned long long* src = (const unsigned long long*)
          (ex + ((((size_t)(t & 1)) * 32 + team) * 8 + rr) * 512 + c0);
      unsigned long long u[8];
      #pragma unroll
      for (int i = 0; i < 8; ++i)
        u[i] = __hip_atomic_load(src + i, __ATOMIC_RELAXED, __HIP_MEMORY_SCOPE_AGENT);
      short8 h0v, h1v, l0v, l1v;
      #pragma unroll
      for (int i = 0; i < 8; ++i){
        unsigned a = (unsigned)u[i];
        unsigned b = (unsigned)(u[i] >> 32);
        short ha = (short)(a >> 16), la = (short)(a & 0xffffu);
        short hb = (short)(b >> 16), lb = (short)(b & 0xffffu);
        if (i < 4){ h0v[2*i] = ha; h0v[2*i+1] = hb; l0v[2*i] = la; l0v[2*i+1] = lb; }
        else      { h1v[2*(i-4)] = ha; h1v[2*(i-4)+1] = hb; l1v[2*(i-4)] = la; l1v[2*(i-4)+1] = lb; }
      }
      *(short8*)&hh[HIDX(rr, c0)]     = h0v;
      *(short8*)&hh[HIDX(rr, c0 + 8)] = h1v;
      *(short8*)&hl[HIDX(rr, c0)]     = l0v;
      *(short8*)&hl[HIDX(rr, c0 + 8)] = l1v;
      __syncthreads();
    }

    // prefetch xproj for this lane's two elements (hidden under MFMA)
    const float* xpb = (t < 128) ? xp0 : xp1;
    const int tt = (t < 128) ? t : t - 128;
    const float xv0 = xpb[((size_t)tt * 256 + b0 + m_0) * 512 + n];
    const float xv1 = xpb[((size_t)tt * 256 + b0 + m_1) * 512 + n];

    // MFMA: 3 independent accumulator chains (hh, hl, lh)
    f32x4 ahh = {}, ahl = {}, alh = {};
    #pragma unroll
    for (int ks = 0; ks < 16; ++ks){
      short8 Ah = *(const short8*)&hh[HIDX(am, ks * 32 + kb)];
      short8 Al = *(const short8*)&hl[HIDX(am, ks * 32 + kb)];
      ahh = __builtin_amdgcn_mfma_f32_16x16x32_bf16(Ah, Bh[ks], ahh, 0, 0, 0);
      ahl = __builtin_amdgcn_mfma_f32_16x16x32_bf16(Ah, Bl[ks], ahl, 0, 0, 0);
      alh = __builtin_amdgcn_mfma_f32_16x16x32_bf16(Al, Bh[ks], alh, 0, 0, 0);
    }
    const float s0 = ahh[0] + (ahl[0] + alh[0]);
    const float s1 = ahh[1] + (ahl[1] + alh[1]);
    const float s2 = ahh[2] + (ahl[2] + alh[2]);
    const float s3 = ahh[3] + (ahl[3] + alh[3]);
    const float t2 = __shfl(s2, lane ^ 32);
    const float t3 = __shfl(s3, lane ^ 32);
    const float v0 = islo ? s0 : t2;
    const float v1 = islo ? s1 : t3;

    const float hn0 = tanh_fast(xv0 + v0) + hr0;
    const float hn1 = tanh_fast(xv1 + v1) + hr1;
    hr0 = hn0; hr1 = hn1;
    states[((size_t)(b0 + m_0) * 256 + t) * 512 + n] = f2bf(hn0);
    states[((size_t)(b0 + m_1) * 256 + t) * 512 + n] = f2bf(hn1);

    if (t < 255){
      unsigned* dst = ex + ((((size_t)((t + 1) & 1)) * 32 + team) * 8) * 512;
      __hip_atomic_store(dst + (size_t)m_0 * 512 + n, pack2(hn0),
                         __ATOMIC_RELAXED, __HIP_MEMORY_SCOPE_AGENT);
      __hip_atomic_store(dst + (size_t)m_1 * 512 + n, pack2(hn1),
                         __ATOMIC_RELAXED, __HIP_MEMORY_SCOPE_AGENT);
      __syncthreads();   // drains all vm stores of the block
      if (tid == 0)
        __hip_atomic_fetch_add(cnt + team * 32, 1u, __ATOMIC_RELEASE,
                               __HIP_MEMORY_SCOPE_AGENT);
    }
  }
}

// ---------------------------------------------------------------------------
// K4: single-precision bf16 GEMM for the output projection (fp32 out).
// ---------------------------------------------------------------------------
__global__ __launch_bounds__(256) void gemm_bias_f32(
    const short* __restrict__ A, const short* __restrict__ Bt,
    const float* __restrict__ bias, float* __restrict__ C,
    int M, int N, int K)
{
  __shared__ short lA[64][72];
  __shared__ short lB[64][72];
  const int m0 = blockIdx.y * 64, n0 = blockIdx.x * 64;
  const int tid = threadIdx.x;
  const int lane = tid & 63, wave = tid >> 6;
  const int wm = (wave >> 1) * 32, wn = (wave & 1) * 32;
  f32x4 acc[2][2] = {};
  for (int k0 = 0; k0 < K; k0 += 64){
    __syncthreads();
    for (int v = tid; v < 512; v += 256){
      int r = v >> 3, c = v & 7;
      *(short8*)&lA[r][c*8] = *(const short8*)(A + (size_t)(m0 + r) * K + k0 + c*8);
      *(short8*)&lB[r][c*8] = *(const short8*)(Bt + (size_t)(n0 + r) * K + k0 + c*8);
    }
    __syncthreads();
    #pragma unroll
    for (int kk = 0; kk < 64; kk += 32){
      int ko = kk + (lane >> 4) * 8;
      short8 a0 = *(const short8*)&lA[wm +      (lane & 15)][ko];
      short8 a1 = *(const short8*)&lA[wm + 16 + (lane & 15)][ko];
      short8 b0 = *(const short8*)&lB[wn +      (lane & 15)][ko];
      short8 b1 = *(const short8*)&lB[wn + 16 + (lane & 15)][ko];
      acc[0][0] = __builtin_amdgcn_mfma_f32_16x16x32_bf16(a0, b0, acc[0][0], 0, 0, 0);
      acc[0][1] = __builtin_amdgcn_mfma_f32_16x16x32_bf16(a0, b1, acc[0][1], 0, 0, 0);
      acc[1][0] = __builtin_amdgcn_mfma_f32_16x16x32_bf16(a1, b0, acc[1][0], 0, 0, 0);
      acc[1][1] = __builtin_amdgcn_mfma_f32_16x16x32_bf16(a1, b1, acc[1][1], 0, 0, 0);
    }
  }
  const int cr = (lane >> 4) * 4, cc = lane & 15;
  #pragma unroll
  for (int i = 0; i < 2; ++i)
  #pragma unroll
  for (int j = 0; j < 2; ++j){
    int row = m0 + wm + i * 16 + cr;
    int col = n0 + wn + j * 16 + cc;
    float bv = bias[col];
    #pragma unroll
    for (int r = 0; r < 4; ++r){
      C[(size_t)(row + r) * N + col] = acc[i][j][r] + bv;
    }
  }
}

// ---------------------------------------------------------------------------
extern "C" void kernel_launch(void* const* d_in, const int* in_sizes, int n_in,
                              void* d_out, int out_size, void* d_ws, size_t ws_size,
                              hipStream_t stream){
  (void)in_sizes; (void)n_in; (void)out_size;
  const float* x    = (const float*)d_in[0];
  const float* Wx   = (const float*)d_in[1];
  const float* Wh   = (const float*)d_in[2];
  const float* bias = (const float*)d_in[3];
  const float* Wout = (const float*)d_in[4];
  const float* bout = (const float*)d_in[5];
  const float* init = (const float*)d_in[6];
  float* out = (float*)d_out;

  char* p = (char*)d_ws;
  // [0,64Mi): xT hi+lo during GEMM1, then states (written only by rnn).
  short* xTh    = (short*)(p);
  short* xTl    = (short*)(p + 33554432);
  short* states = (short*)(p);
  // xproj fp32: rows [0,32768) in ws, rows [32768,65536) in d_out (dead until GEMM2).
  float* xproj0 = (float*)(p + 67108864);     // 64 MiB
  float* xproj1 = (float*)d_out;              // 64 MiB
  short* WxTh   = (short*)(p + 134217728);    // 256 KiB
  short* WxTl   = (short*)(p + 134479872);    // 256 KiB
  short* WhTh   = (short*)(p + 134742016);    // 512 KiB
  short* WhTl   = (short*)(p + 135266304);    // 512 KiB
  short* WoutT  = (short*)(p + 135790592);    // 256 KiB
  unsigned* ex  = (unsigned*)(p + 136052736); // 1 MiB   [2][32][8][512]
  unsigned* cnt = (unsigned*)(p + 137101312); // 4 KiB   [32] stride-32 uints
  if (ws_size < 137105408u){
    fprintf(stderr, "kernel_launch: ws_size=%zu < 137105408 needed\n", ws_size);
  }

  // reset team counters every launch (graph-capture-safe)
  hipMemsetAsync(cnt, 0, 4096, stream);

  transpose_split<<<(256*512 + 255)/256, 256, 0, stream>>>(Wx, WxTh, WxTl, 256, 512);
  transpose_split<<<(512*512 + 255)/256, 256, 0, stream>>>(Wh, WhTh, WhTl, 512, 512);
  transpose_to_bf16<<<(512*256 + 255)/256, 256, 0, stream>>>(Wout, WoutT, 512, 256);
  transpose_x_split<<<dim3(256, 4, 4), 256, 0, stream>>>(x, xTh, xTl);
  // xproj = xT @ Wx + b at ~fp32 precision (3-product split MFMA)
  gemm1_split<<<dim3(8, 1024), 256, 0, stream>>>(xTh, xTl, WxTh, WxTl, bias,
                                                 xproj0, xproj1, 65536, 512, 256);
  // recurrence: 32 teams x 8 slices
  rnn_steps_v3<<<256, 256, 0, stream>>>(xproj0, xproj1, WhTh, WhTl, init,
                                        states, ex, cnt);
  // out = states @ Wout + bout (single bf16 product)
  gemm_bias_f32<<<dim3(4, 1024), 256, 0, stream>>>(states, WoutT, bout, out, 65536, 256, 512);
}

// Round 4
// 1275.068 us; speedup vs baseline: 4.6088x; 1.9907x over previous
//
#include <hip/hip_runtime.h>
#include <cstring>
#include <cstdio>

typedef __attribute__((ext_vector_type(8))) short short8;
typedef __attribute__((ext_vector_type(4))) float f32x4;
typedef __attribute__((ext_vector_type(4))) unsigned u32x4;

__device__ __forceinline__ short f2bf(float f){
  unsigned u; __builtin_memcpy(&u, &f, 4);
  u += 0x7FFFu + ((u >> 16) & 1u);
  return (short)(u >> 16);
}
__device__ __forceinline__ float bf2f(short s){
  unsigned u = ((unsigned)(unsigned short)s) << 16;
  float f; __builtin_memcpy(&f, &u, 4);
  return f;
}
__device__ __forceinline__ void split2(float v, short& hi, short& lo){
  hi = f2bf(v);
  float r = v - bf2f(hi);   // exact (Sterbenz)
  lo = f2bf(r);
}
__device__ __forceinline__ unsigned pack2(float v){
  short hi, lo; split2(v, hi, lo);
  return (((unsigned)(unsigned short)hi) << 16) | (unsigned)(unsigned short)lo;
}
__device__ __forceinline__ float tanh_fast(float x){
  float e = __expf(2.0f * x);
  return 1.0f - 2.0f / (e + 1.0f);
}

// swizzled LDS short-index for h planes: element (r,k) -> idx, XOR bits 3..5
#define HIDX(r,k) ((((r) * 512) + (k)) ^ (((r) & 7) << 3))

// ---------------------------------------------------------------------------
// K0a: transpose + hi/lo split: outh[c][r] + outl[c][r] = split(in[r][c])
// ---------------------------------------------------------------------------
__global__ void transpose_split(const float* __restrict__ in,
                                short* __restrict__ outh, short* __restrict__ outl,
                                int R, int C){
  int idx = blockIdx.x * 256 + threadIdx.x;
  if (idx < R * C){
    int r = idx / C, c = idx % C;
    short h, l; split2(in[(size_t)r * C + c], h, l);
    outh[(size_t)c * R + r] = h;
    outl[(size_t)c * R + r] = l;
  }
}

// K0b: plain transpose to single bf16 (for Wout)
__global__ void transpose_to_bf16(const float* __restrict__ in, short* __restrict__ out,
                                  int R, int C){
  int idx = blockIdx.x * 256 + threadIdx.x;
  if (idx < R * C){
    int r = idx / C, c = idx % C;
    out[(size_t)c * R + r] = f2bf(in[(size_t)r * C + c]);
  }
}

// ---------------------------------------------------------------------------
// K1: x [B=256][D=256][T=256] f32 -> xT_hi/xT_lo [(t*256+b)][d] bf16
// ---------------------------------------------------------------------------
__global__ __launch_bounds__(256) void transpose_x_split(const float* __restrict__ x,
                                                         short* __restrict__ xTh,
                                                         short* __restrict__ xTl){
  __shared__ float tile[64][65];
  const int b = blockIdx.x, d0 = blockIdx.y * 64, t0 = blockIdx.z * 64;
  const int tid = threadIdx.x;
  const float* xp = x + ((size_t)b * 256 + d0) * 256 + t0;
  for (int v = tid; v < 1024; v += 256){
    int r = v >> 4, c4 = (v & 15) * 4;
    float4 f = *(const float4*)(xp + (size_t)r * 256 + c4);
    tile[r][c4+0] = f.x; tile[r][c4+1] = f.y; tile[r][c4+2] = f.z; tile[r][c4+3] = f.w;
  }
  __syncthreads();
  for (int v = tid; v < 512; v += 256){
    int j = v >> 3, i8 = (v & 7) * 8;
    short8 oh, ol;
    #pragma unroll
    for (int u = 0; u < 8; ++u){ short h, l; split2(tile[i8 + u][j], h, l); oh[u] = h; ol[u] = l; }
    size_t off = ((size_t)(t0 + j) * 256 + b) * 256 + d0 + i8;
    *(short8*)(xTh + off) = oh;
    *(short8*)(xTl + off) = ol;
  }
}

// ---------------------------------------------------------------------------
// K2: split-precision GEMM (3-product): C = (Ah+Al)@(Bh+Bl)^T + bias, fp32 out.
// Output rows < 32768 -> C0, else C1 (row-32768).
// ---------------------------------------------------------------------------
__global__ __launch_bounds__(256) void gemm1_split(
    const short* __restrict__ Ah, const short* __restrict__ Al,
    const short* __restrict__ Bh, const short* __restrict__ Bl,
    const float* __restrict__ bias, float* __restrict__ C0, float* __restrict__ C1,
    int M, int N, int K)
{
  __shared__ short lAh[64][72];
  __shared__ short lAl[64][72];
  __shared__ short lBh[64][72];
  __shared__ short lBl[64][72];
  const int m0 = blockIdx.y * 64, n0 = blockIdx.x * 64;
  const int tid = threadIdx.x;
  const int lane = tid & 63, wave = tid >> 6;
  const int wm = (wave >> 1) * 32, wn = (wave & 1) * 32;
  f32x4 acc[2][2] = {};
  for (int k0 = 0; k0 < K; k0 += 64){
    __syncthreads();
    for (int v = tid; v < 2048; v += 256){
      int sel = v >> 9, idx = v & 511;
      int r = idx >> 3, c = (idx & 7) * 8;
      const short* src = (sel == 0) ? Ah + (size_t)(m0 + r) * K + k0 + c
                       : (sel == 1) ? Al + (size_t)(m0 + r) * K + k0 + c
                       : (sel == 2) ? Bh + (size_t)(n0 + r) * K + k0 + c
                                    : Bl + (size_t)(n0 + r) * K + k0 + c;
      short8 val = *(const short8*)src;
      short* dst = (sel == 0) ? &lAh[r][c] : (sel == 1) ? &lAl[r][c]
                 : (sel == 2) ? &lBh[r][c] : &lBl[r][c];
      *(short8*)dst = val;
    }
    __syncthreads();
    #pragma unroll
    for (int kk = 0; kk < 64; kk += 32){
      int ko = kk + (lane >> 4) * 8;
      short8 ah0 = *(const short8*)&lAh[wm +      (lane & 15)][ko];
      short8 ah1 = *(const short8*)&lAh[wm + 16 + (lane & 15)][ko];
      short8 al0 = *(const short8*)&lAl[wm +      (lane & 15)][ko];
      short8 al1 = *(const short8*)&lAl[wm + 16 + (lane & 15)][ko];
      short8 bh0 = *(const short8*)&lBh[wn +      (lane & 15)][ko];
      short8 bh1 = *(const short8*)&lBh[wn + 16 + (lane & 15)][ko];
      short8 bl0 = *(const short8*)&lBl[wn +      (lane & 15)][ko];
      short8 bl1 = *(const short8*)&lBl[wn + 16 + (lane & 15)][ko];
      acc[0][0] = __builtin_amdgcn_mfma_f32_16x16x32_bf16(ah0, bh0, acc[0][0], 0, 0, 0);
      acc[0][1] = __builtin_amdgcn_mfma_f32_16x16x32_bf16(ah0, bh1, acc[0][1], 0, 0, 0);
      acc[1][0] = __builtin_amdgcn_mfma_f32_16x16x32_bf16(ah1, bh0, acc[1][0], 0, 0, 0);
      acc[1][1] = __builtin_amdgcn_mfma_f32_16x16x32_bf16(ah1, bh1, acc[1][1], 0, 0, 0);
      acc[0][0] = __builtin_amdgcn_mfma_f32_16x16x32_bf16(ah0, bl0, acc[0][0], 0, 0, 0);
      acc[0][1] = __builtin_amdgcn_mfma_f32_16x16x32_bf16(ah0, bl1, acc[0][1], 0, 0, 0);
      acc[1][0] = __builtin_amdgcn_mfma_f32_16x16x32_bf16(ah1, bl0, acc[1][0], 0, 0, 0);
      acc[1][1] = __builtin_amdgcn_mfma_f32_16x16x32_bf16(ah1, bl1, acc[1][1], 0, 0, 0);
      acc[0][0] = __builtin_amdgcn_mfma_f32_16x16x32_bf16(al0, bh0, acc[0][0], 0, 0, 0);
      acc[0][1] = __builtin_amdgcn_mfma_f32_16x16x32_bf16(al0, bh1, acc[0][1], 0, 0, 0);
      acc[1][0] = __builtin_amdgcn_mfma_f32_16x16x32_bf16(al1, bh0, acc[1][0], 0, 0, 0);
      acc[1][1] = __builtin_amdgcn_mfma_f32_16x16x32_bf16(al1, bh1, acc[1][1], 0, 0, 0);
    }
  }
  const int cr = (lane >> 4) * 4, cc = lane & 15;
  #pragma unroll
  for (int i = 0; i < 2; ++i)
  #pragma unroll
  for (int j = 0; j < 2; ++j){
    int row = m0 + wm + i * 16 + cr;
    int col = n0 + wn + j * 16 + cc;
    float bv = bias[col];
    float* base = (row < 32768) ? C0 : C1;
    int rr = (row < 32768) ? row : row - 32768;
    #pragma unroll
    for (int r = 0; r < 4; ++r){
      base[(size_t)(rr + r) * N + col] = acc[i][j][r] + bv;
    }
  }
}

// ---------------------------------------------------------------------------
// K3 v4: team-parallel recurrence. 256 blocks = 32 teams x 8 N-slices.
// Wh slice pinned in 128 VGPRs (asm-pinned, no remat). Exchange via
// tag-embedded u64 words [tag32|payload32], inline-asm sc0 sc1 stores/loads,
// batched polling with a single vmcnt(0) per poll round. Parity double-buffer.
// ---------------------------------------------------------------------------
__global__ __launch_bounds__(256, 1) void rnn_steps_v4(
    const float* __restrict__ xp0,    // t<128:  [(t*256+b)][512] f32
    const float* __restrict__ xp1,    // t>=128: [((t-128)*256+b)][512] f32
    const short* __restrict__ WhTh,   // [512][512] bf16 hi, [n][k]
    const short* __restrict__ WhTl,   // [512][512] bf16 lo
    const float* __restrict__ init,   // [512]
    short* __restrict__ states,       // [(b*256+t)][512] bf16
    unsigned long long* __restrict__ ex)  // [2][32][8][512] u64 [tag|payload]
{
  __shared__ short hh[16 * 512];      // h hi plane, swizzled, rows 8..15 zero
  __shared__ short hl[16 * 512];      // h lo plane
  const int tid = threadIdx.x, lane = tid & 63, wave = tid >> 6;
  const int team = blockIdx.x & 31, slice = blockIdx.x >> 5;
  const int b0 = team * 8;
  const int nc = slice * 64 + wave * 16;          // this wave's global col base

  // ---- prologue: Wh B-fragments into registers (hi+lo, 16 k-steps) ----
  short8 Bh[16], Bl[16];
  {
    const size_t col = (size_t)(nc + (lane & 15));
    const int kb = (lane >> 4) * 8;
    #pragma unroll
    for (int ks = 0; ks < 16; ++ks){
      Bh[ks] = *(const short8*)(WhTh + col * 512 + ks * 32 + kb);
      Bl[ks] = *(const short8*)(WhTl + col * 512 + ks * 32 + kb);
    }
    // pin in VGPRs: opaque asm outputs cannot be rematerialized from memory
    #pragma unroll
    for (int ks = 0; ks < 16; ++ks){
      asm volatile("" : "+v"(Bh[ks]), "+v"(Bl[ks]));
    }
  }
  // zero pad rows 8..15 once; fill rows 0..7 with init
  for (int v = tid; v < 8 * 512; v += 256){
    int r = 8 + (v >> 9), k = v & 511;
    hh[HIDX(r, k)] = 0; hl[HIDX(r, k)] = 0;
  }
  for (int v = tid; v < 8 * 512; v += 256){
    int r = v >> 9, k = v & 511;
    short hi, lo; split2(init[k], hi, lo);
    hh[HIDX(r, k)] = hi; hl[HIDX(r, k)] = lo;
  }
  __syncthreads();

  // ---- per-lane epilogue constants (same mapping as verified r2/r3) ----
  const int cc = lane & 15;
  const bool islo = (lane < 32);
  const int mbase = ((lane & 31) >> 4) * 4;
  const int m_0 = mbase + (islo ? 0 : 2);
  const int m_1 = mbase + (islo ? 1 : 3);
  const int n = nc + cc;                           // global col of this lane
  float hr0 = init[n], hr1 = init[n];              // fp32 residual masters

  const int am = lane & 15, kb = (lane >> 4) * 8;
  const int rr = tid >> 5, c0 = (tid & 31) * 16;   // exchange-read assignment

  for (int t = 0; t < 256; ++t){
    // prefetch xproj for this lane's two elements (overlaps poll/MFMA)
    const float* xpb = (t < 128) ? xp0 : xp1;
    const int tt = (t < 128) ? t : t - 128;
    const float xv0 = xpb[((size_t)tt * 256 + b0 + m_0) * 512 + n];
    const float xv1 = xpb[((size_t)tt * 256 + b0 + m_1) * 512 + n];

    if (t > 0){
      // poll team slot buf[t&1] until all 16 words (this thread's share of
      // full h_t) carry tag == t. Words: [row rr][cols c0..c0+15].
      const unsigned long long* src =
          ex + ((((size_t)(t & 1)) * 32 + team) * 8 + rr) * 512 + c0;
      u32x4 g[8];
      const unsigned tagv = (unsigned)t;
      bool need0 = true, need1 = true, need2 = true, need3 = true;
      bool need4 = true, need5 = true, need6 = true, need7 = true;
      while (true){
        if (need0) asm volatile("global_load_dwordx4 %0, %1, off sc0 sc1" : "=&v"(g[0]) : "v"(src +  0) : "memory");
        if (need1) asm volatile("global_load_dwordx4 %0, %1, off sc0 sc1" : "=&v"(g[1]) : "v"(src +  2) : "memory");
        if (need2) asm volatile("global_load_dwordx4 %0, %1, off sc0 sc1" : "=&v"(g[2]) : "v"(src +  4) : "memory");
        if (need3) asm volatile("global_load_dwordx4 %0, %1, off sc0 sc1" : "=&v"(g[3]) : "v"(src +  6) : "memory");
        if (need4) asm volatile("global_load_dwordx4 %0, %1, off sc0 sc1" : "=&v"(g[4]) : "v"(src +  8) : "memory");
        if (need5) asm volatile("global_load_dwordx4 %0, %1, off sc0 sc1" : "=&v"(g[5]) : "v"(src + 10) : "memory");
        if (need6) asm volatile("global_load_dwordx4 %0, %1, off sc0 sc1" : "=&v"(g[6]) : "v"(src + 12) : "memory");
        if (need7) asm volatile("global_load_dwordx4 %0, %1, off sc0 sc1" : "=&v"(g[7]) : "v"(src + 14) : "memory");
        // one wait for the whole batch; "+v" deps stop tag checks hoisting
        asm volatile("s_waitcnt vmcnt(0)"
                     : "+v"(g[0]), "+v"(g[1]), "+v"(g[2]), "+v"(g[3]),
                       "+v"(g[4]), "+v"(g[5]), "+v"(g[6]), "+v"(g[7]) :: "memory");
        need0 = (g[0].y != tagv) | (g[0].w != tagv);
        need1 = (g[1].y != tagv) | (g[1].w != tagv);
        need2 = (g[2].y != tagv) | (g[2].w != tagv);
        need3 = (g[3].y != tagv) | (g[3].w != tagv);
        need4 = (g[4].y != tagv) | (g[4].w != tagv);
        need5 = (g[5].y != tagv) | (g[5].w != tagv);
        need6 = (g[6].y != tagv) | (g[6].w != tagv);
        need7 = (g[7].y != tagv) | (g[7].w != tagv);
        if (!(need0 | need1 | need2 | need3 | need4 | need5 | need6 | need7)) break;
        __builtin_amdgcn_s_sleep(1);
      }
      // unpack payloads -> LDS hi/lo planes
      short8 h0v, h1v, l0v, l1v;
      #pragma unroll
      for (int i = 0; i < 4; ++i){
        unsigned pa = g[i].x,     pb = g[i].z;      // cols c0+2i, c0+2i+1
        unsigned pc = g[4 + i].x, pd = g[4 + i].z;  // cols c0+8+2i, c0+8+2i+1
        h0v[2*i]   = (short)(pa >> 16); h0v[2*i+1] = (short)(pb >> 16);
        l0v[2*i]   = (short)(pa & 0xffffu); l0v[2*i+1] = (short)(pb & 0xffffu);
        h1v[2*i]   = (short)(pc >> 16); h1v[2*i+1] = (short)(pd >> 16);
        l1v[2*i]   = (short)(pc & 0xffffu); l1v[2*i+1] = (short)(pd & 0xffffu);
      }
      *(short8*)&hh[HIDX(rr, c0)]     = h0v;
      *(short8*)&hh[HIDX(rr, c0 + 8)] = h1v;
      *(short8*)&hl[HIDX(rr, c0)]     = l0v;
      *(short8*)&hl[HIDX(rr, c0 + 8)] = l1v;
      __syncthreads();
    }

    // MFMA: 3 independent accumulator chains (hh, hl, lh)
    f32x4 ahh = {}, ahl = {}, alh = {};
    #pragma unroll
    for (int ks = 0; ks < 16; ++ks){
      short8 Ah = *(const short8*)&hh[HIDX(am, ks * 32 + kb)];
      short8 Al = *(const short8*)&hl[HIDX(am, ks * 32 + kb)];
      ahh = __builtin_amdgcn_mfma_f32_16x16x32_bf16(Ah, Bh[ks], ahh, 0, 0, 0);
      ahl = __builtin_amdgcn_mfma_f32_16x16x32_bf16(Ah, Bl[ks], ahl, 0, 0, 0);
      alh = __builtin_amdgcn_mfma_f32_16x16x32_bf16(Al, Bh[ks], alh, 0, 0, 0);
    }
    const float s0 = ahh[0] + (ahl[0] + alh[0]);
    const float s1 = ahh[1] + (ahl[1] + alh[1]);
    const float s2 = ahh[2] + (ahl[2] + alh[2]);
    const float s3 = ahh[3] + (ahl[3] + alh[3]);
    const float t2 = __shfl(s2, lane ^ 32);
    const float t3 = __shfl(s3, lane ^ 32);
    const float v0 = islo ? s0 : t2;
    const float v1 = islo ? s1 : t3;

    const float hn0 = tanh_fast(xv0 + v0) + hr0;
    const float hn1 = tanh_fast(xv1 + v1) + hr1;
    hr0 = hn0; hr1 = hn1;
    states[((size_t)(b0 + m_0) * 256 + t) * 512 + n] = f2bf(hn0);
    states[((size_t)(b0 + m_1) * 256 + t) * 512 + n] = f2bf(hn1);

    if (t < 255){
      // publish h_{t+1} slice: one 8B store per element, tag = t+1
      const unsigned tagn = (unsigned)(t + 1);
      unsigned long long* dst =
          ex + ((((size_t)((t + 1) & 1)) * 32 + team) * 8) * 512;
      unsigned long long w0 = (((unsigned long long)tagn) << 32) | pack2(hn0);
      unsigned long long w1 = (((unsigned long long)tagn) << 32) | pack2(hn1);
      unsigned long long* a0 = dst + (size_t)m_0 * 512 + n;
      unsigned long long* a1 = dst + (size_t)m_1 * 512 + n;
      asm volatile("global_store_dwordx2 %0, %1, off sc0 sc1" :: "v"(a0), "v"(w0) : "memory");
      asm volatile("global_store_dwordx2 %0, %1, off sc0 sc1" :: "v"(a1), "v"(w1) : "memory");
    }
  }
}

// ---------------------------------------------------------------------------
// K4: single-precision bf16 GEMM for the output projection (fp32 out).
// ---------------------------------------------------------------------------
__global__ __launch_bounds__(256) void gemm_bias_f32(
    const short* __restrict__ A, const short* __restrict__ Bt,
    const float* __restrict__ bias, float* __restrict__ C,
    int M, int N, int K)
{
  __shared__ short lA[64][72];
  __shared__ short lB[64][72];
  const int m0 = blockIdx.y * 64, n0 = blockIdx.x * 64;
  const int tid = threadIdx.x;
  const int lane = tid & 63, wave = tid >> 6;
  const int wm = (wave >> 1) * 32, wn = (wave & 1) * 32;
  f32x4 acc[2][2] = {};
  for (int k0 = 0; k0 < K; k0 += 64){
    __syncthreads();
    for (int v = tid; v < 512; v += 256){
      int r = v >> 3, c = v & 7;
      *(short8*)&lA[r][c*8] = *(const short8*)(A + (size_t)(m0 + r) * K + k0 + c*8);
      *(short8*)&lB[r][c*8] = *(const short8*)(Bt + (size_t)(n0 + r) * K + k0 + c*8);
    }
    __syncthreads();
    #pragma unroll
    for (int kk = 0; kk < 64; kk += 32){
      int ko = kk + (lane >> 4) * 8;
      short8 a0 = *(const short8*)&lA[wm +      (lane & 15)][ko];
      short8 a1 = *(const short8*)&lA[wm + 16 + (lane & 15)][ko];
      short8 b0 = *(const short8*)&lB[wn +      (lane & 15)][ko];
      short8 b1 = *(const short8*)&lB[wn + 16 + (lane & 15)][ko];
      acc[0][0] = __builtin_amdgcn_mfma_f32_16x16x32_bf16(a0, b0, acc[0][0], 0, 0, 0);
      acc[0][1] = __builtin_amdgcn_mfma_f32_16x16x32_bf16(a0, b1, acc[0][1], 0, 0, 0);
      acc[1][0] = __builtin_amdgcn_mfma_f32_16x16x32_bf16(a1, b0, acc[1][0], 0, 0, 0);
      acc[1][1] = __builtin_amdgcn_mfma_f32_16x16x32_bf16(a1, b1, acc[1][1], 0, 0, 0);
    }
  }
  const int cr = (lane >> 4) * 4, cc = lane & 15;
  #pragma unroll
  for (int i = 0; i < 2; ++i)
  #pragma unroll
  for (int j = 0; j < 2; ++j){
    int row = m0 + wm + i * 16 + cr;
    int col = n0 + wn + j * 16 + cc;
    float bv = bias[col];
    #pragma unroll
    for (int r = 0; r < 4; ++r){
      C[(size_t)(row + r) * N + col] = acc[i][j][r] + bv;
    }
  }
}

// ---------------------------------------------------------------------------
extern "C" void kernel_launch(void* const* d_in, const int* in_sizes, int n_in,
                              void* d_out, int out_size, void* d_ws, size_t ws_size,
                              hipStream_t stream){
  (void)in_sizes; (void)n_in; (void)out_size;
  const float* x    = (const float*)d_in[0];
  const float* Wx   = (const float*)d_in[1];
  const float* Wh   = (const float*)d_in[2];
  const float* bias = (const float*)d_in[3];
  const float* Wout = (const float*)d_in[4];
  const float* bout = (const float*)d_in[5];
  const float* init = (const float*)d_in[6];
  float* out = (float*)d_out;

  char* p = (char*)d_ws;
  // [0,64Mi): xT hi+lo during GEMM1, then states (written only by rnn).
  short* xTh    = (short*)(p);
  short* xTl    = (short*)(p + 33554432);
  short* states = (short*)(p);
  // xproj fp32: rows [0,32768) in ws, rows [32768,65536) in d_out (dead until GEMM2).
  float* xproj0 = (float*)(p + 67108864);     // 64 MiB
  float* xproj1 = (float*)d_out;              // 64 MiB
  short* WxTh   = (short*)(p + 134217728);    // 256 KiB
  short* WxTl   = (short*)(p + 134479872);    // 256 KiB
  short* WhTh   = (short*)(p + 134742016);    // 512 KiB
  short* WhTl   = (short*)(p + 135266304);    // 512 KiB
  short* WoutT  = (short*)(p + 135790592);    // 256 KiB
  unsigned long long* ex = (unsigned long long*)(p + 136052736); // 2 MiB [2][32][8][512]
  if (ws_size < 138149888u){
    fprintf(stderr, "kernel_launch: ws_size=%zu < 138149888 needed\n", ws_size);
  }

  // clear exchange tags every launch (graph-capture-safe)
  hipMemsetAsync(ex, 0, 2097152, stream);

  transpose_split<<<(256*512 + 255)/256, 256, 0, stream>>>(Wx, WxTh, WxTl, 256, 512);
  transpose_split<<<(512*512 + 255)/256, 256, 0, stream>>>(Wh, WhTh, WhTl, 512, 512);
  transpose_to_bf16<<<(512*256 + 255)/256, 256, 0, stream>>>(Wout, WoutT, 512, 256);
  transpose_x_split<<<dim3(256, 4, 4), 256, 0, stream>>>(x, xTh, xTl);
  // xproj = xT @ Wx + b at ~fp32 precision (3-product split MFMA)
  gemm1_split<<<dim3(8, 1024), 256, 0, stream>>>(xTh, xTl, WxTh, WxTl, bias,
                                                 xproj0, xproj1, 65536, 512, 256);
  // recurrence: 32 teams x 8 slices, tag-embedded exchange
  rnn_steps_v4<<<256, 256, 0, stream>>>(xproj0, xproj1, WhTh, WhTl, init,
                                        states, ex);
  // out = states @ Wout + bout (single bf16 product)
  gemm_bias_f32<<<dim3(4, 1024), 256, 0, stream>>>(states, WoutT, bout, out, 65536, 256, 512);
}

// Round 5
// 903.868 us; speedup vs baseline: 6.5016x; 1.4107x over previous
//
#include <hip/hip_runtime.h>
#include <cstring>
#include <cstdio>

typedef __attribute__((ext_vector_type(8))) short short8;
typedef __attribute__((ext_vector_type(4))) float f32x4;
typedef __attribute__((ext_vector_type(4))) unsigned u32x4;

__device__ __forceinline__ short f2bf(float f){
  unsigned u; __builtin_memcpy(&u, &f, 4);
  u += 0x7FFFu + ((u >> 16) & 1u);
  return (short)(u >> 16);
}
__device__ __forceinline__ float bf2f(short s){
  unsigned u = ((unsigned)(unsigned short)s) << 16;
  float f; __builtin_memcpy(&f, &u, 4);
  return f;
}
__device__ __forceinline__ void split2(float v, short& hi, short& lo){
  hi = f2bf(v);
  float r = v - bf2f(hi);   // exact (Sterbenz)
  lo = f2bf(r);
}
__device__ __forceinline__ unsigned pack2(float v){
  short hi, lo; split2(v, hi, lo);
  return (((unsigned)(unsigned short)hi) << 16) | (unsigned)(unsigned short)lo;
}
__device__ __forceinline__ float tanh_fast(float x){
  float e = __expf(2.0f * x);
  return 1.0f - 2.0f / (e + 1.0f);
}

// swizzled LDS short-index for h planes: element (r,k) -> idx, XOR bits 3..5
#define HIDX(r,k) ((((r) * 512) + (k)) ^ (((r) & 7) << 3))

// ---------------------------------------------------------------------------
// K0a: transpose + hi/lo split: outh[c][r] + outl[c][r] = split(in[r][c])
// ---------------------------------------------------------------------------
__global__ void transpose_split(const float* __restrict__ in,
                                short* __restrict__ outh, short* __restrict__ outl,
                                int R, int C){
  int idx = blockIdx.x * 256 + threadIdx.x;
  if (idx < R * C){
    int r = idx / C, c = idx % C;
    short h, l; split2(in[(size_t)r * C + c], h, l);
    outh[(size_t)c * R + r] = h;
    outl[(size_t)c * R + r] = l;
  }
}

// K0b: plain transpose to single bf16 (for Wout)
__global__ void transpose_to_bf16(const float* __restrict__ in, short* __restrict__ out,
                                  int R, int C){
  int idx = blockIdx.x * 256 + threadIdx.x;
  if (idx < R * C){
    int r = idx / C, c = idx % C;
    out[(size_t)c * R + r] = f2bf(in[(size_t)r * C + c]);
  }
}

// ---------------------------------------------------------------------------
// K1: x [B=256][D=256][T=256] f32 -> xT_hi/xT_lo [(t*256+b)][d] bf16
// ---------------------------------------------------------------------------
__global__ __launch_bounds__(256) void transpose_x_split(const float* __restrict__ x,
                                                         short* __restrict__ xTh,
                                                         short* __restrict__ xTl){
  __shared__ float tile[64][65];
  const int b = blockIdx.x, d0 = blockIdx.y * 64, t0 = blockIdx.z * 64;
  const int tid = threadIdx.x;
  const float* xp = x + ((size_t)b * 256 + d0) * 256 + t0;
  for (int v = tid; v < 1024; v += 256){
    int r = v >> 4, c4 = (v & 15) * 4;
    float4 f = *(const float4*)(xp + (size_t)r * 256 + c4);
    tile[r][c4+0] = f.x; tile[r][c4+1] = f.y; tile[r][c4+2] = f.z; tile[r][c4+3] = f.w;
  }
  __syncthreads();
  for (int v = tid; v < 512; v += 256){
    int j = v >> 3, i8 = (v & 7) * 8;
    short8 oh, ol;
    #pragma unroll
    for (int u = 0; u < 8; ++u){ short h, l; split2(tile[i8 + u][j], h, l); oh[u] = h; ol[u] = l; }
    size_t off = ((size_t)(t0 + j) * 256 + b) * 256 + d0 + i8;
    *(short8*)(xTh + off) = oh;
    *(short8*)(xTl + off) = ol;
  }
}

// ---------------------------------------------------------------------------
// K2: split-precision GEMM (3-product): C = (Ah+Al)@(Bh+Bl)^T + bias, fp32 out.
// Output rows < 32768 -> C0, else C1 (row-32768).
// ---------------------------------------------------------------------------
__global__ __launch_bounds__(256) void gemm1_split(
    const short* __restrict__ Ah, const short* __restrict__ Al,
    const short* __restrict__ Bh, const short* __restrict__ Bl,
    const float* __restrict__ bias, float* __restrict__ C0, float* __restrict__ C1,
    int M, int N, int K)
{
  __shared__ short lAh[64][72];
  __shared__ short lAl[64][72];
  __shared__ short lBh[64][72];
  __shared__ short lBl[64][72];
  const int m0 = blockIdx.y * 64, n0 = blockIdx.x * 64;
  const int tid = threadIdx.x;
  const int lane = tid & 63, wave = tid >> 6;
  const int wm = (wave >> 1) * 32, wn = (wave & 1) * 32;
  f32x4 acc[2][2] = {};
  for (int k0 = 0; k0 < K; k0 += 64){
    __syncthreads();
    for (int v = tid; v < 2048; v += 256){
      int sel = v >> 9, idx = v & 511;
      int r = idx >> 3, c = (idx & 7) * 8;
      const short* src = (sel == 0) ? Ah + (size_t)(m0 + r) * K + k0 + c
                       : (sel == 1) ? Al + (size_t)(m0 + r) * K + k0 + c
                       : (sel == 2) ? Bh + (size_t)(n0 + r) * K + k0 + c
                                    : Bl + (size_t)(n0 + r) * K + k0 + c;
      short8 val = *(const short8*)src;
      short* dst = (sel == 0) ? &lAh[r][c] : (sel == 1) ? &lAl[r][c]
                 : (sel == 2) ? &lBh[r][c] : &lBl[r][c];
      *(short8*)dst = val;
    }
    __syncthreads();
    #pragma unroll
    for (int kk = 0; kk < 64; kk += 32){
      int ko = kk + (lane >> 4) * 8;
      short8 ah0 = *(const short8*)&lAh[wm +      (lane & 15)][ko];
      short8 ah1 = *(const short8*)&lAh[wm + 16 + (lane & 15)][ko];
      short8 al0 = *(const short8*)&lAl[wm +      (lane & 15)][ko];
      short8 al1 = *(const short8*)&lAl[wm + 16 + (lane & 15)][ko];
      short8 bh0 = *(const short8*)&lBh[wn +      (lane & 15)][ko];
      short8 bh1 = *(const short8*)&lBh[wn + 16 + (lane & 15)][ko];
      short8 bl0 = *(const short8*)&lBl[wn +      (lane & 15)][ko];
      short8 bl1 = *(const short8*)&lBl[wn + 16 + (lane & 15)][ko];
      acc[0][0] = __builtin_amdgcn_mfma_f32_16x16x32_bf16(ah0, bh0, acc[0][0], 0, 0, 0);
      acc[0][1] = __builtin_amdgcn_mfma_f32_16x16x32_bf16(ah0, bh1, acc[0][1], 0, 0, 0);
      acc[1][0] = __builtin_amdgcn_mfma_f32_16x16x32_bf16(ah1, bh0, acc[1][0], 0, 0, 0);
      acc[1][1] = __builtin_amdgcn_mfma_f32_16x16x32_bf16(ah1, bh1, acc[1][1], 0, 0, 0);
      acc[0][0] = __builtin_amdgcn_mfma_f32_16x16x32_bf16(ah0, bl0, acc[0][0], 0, 0, 0);
      acc[0][1] = __builtin_amdgcn_mfma_f32_16x16x32_bf16(ah0, bl1, acc[0][1], 0, 0, 0);
      acc[1][0] = __builtin_amdgcn_mfma_f32_16x16x32_bf16(ah1, bl0, acc[1][0], 0, 0, 0);
      acc[1][1] = __builtin_amdgcn_mfma_f32_16x16x32_bf16(ah1, bl1, acc[1][1], 0, 0, 0);
      acc[0][0] = __builtin_amdgcn_mfma_f32_16x16x32_bf16(al0, bh0, acc[0][0], 0, 0, 0);
      acc[0][1] = __builtin_amdgcn_mfma_f32_16x16x32_bf16(al0, bh1, acc[0][1], 0, 0, 0);
      acc[1][0] = __builtin_amdgcn_mfma_f32_16x16x32_bf16(al1, bh0, acc[1][0], 0, 0, 0);
      acc[1][1] = __builtin_amdgcn_mfma_f32_16x16x32_bf16(al1, bh1, acc[1][1], 0, 0, 0);
    }
  }
  const int cr = (lane >> 4) * 4, cc = lane & 15;
  #pragma unroll
  for (int i = 0; i < 2; ++i)
  #pragma unroll
  for (int j = 0; j < 2; ++j){
    int row = m0 + wm + i * 16 + cr;
    int col = n0 + wn + j * 16 + cc;
    float bv = bias[col];
    float* base = (row < 32768) ? C0 : C1;
    int rr = (row < 32768) ? row : row - 32768;
    #pragma unroll
    for (int r = 0; r < 4; ++r){
      base[(size_t)(rr + r) * N + col] = acc[i][j][r] + bv;
    }
  }
}

// ---------------------------------------------------------------------------
// K3 v5: team-parallel recurrence, flag-gated exchange.
// 256 blocks = 32 teams x 8 N-slices. Wh slice pinned in regs. Payload = u32
// (bf16hi|bf16lo), parity double-buffer. Readiness: 1 flag/producer-block,
// posted after per-thread vmcnt(0) drain + block barrier. Readers poll the
// team's 8 flags as two wave-uniform dwordx4 (1 L3 RT/round), then bulk-read
// payload with one vmcnt(0).
// ---------------------------------------------------------------------------
__global__ __launch_bounds__(256, 1) void rnn_steps_v5(
    const float* __restrict__ xp0,    // t<128:  [(t*256+b)][512] f32
    const float* __restrict__ xp1,    // t>=128: [((t-128)*256+b)][512] f32
    const short* __restrict__ WhTh,   // [512][512] bf16 hi, [n][k]
    const short* __restrict__ WhTl,   // [512][512] bf16 lo
    const float* __restrict__ init,   // [512]
    short* __restrict__ states,       // [(b*256+t)][512] bf16
    unsigned* __restrict__ pay,       // [2][32][8][512] u32 payload
    unsigned* __restrict__ flags)     // [2][32][32] u32 (8 used/team, 128B stride)
{
  __shared__ short hh[16 * 512];      // h hi plane, swizzled, rows 8..15 zero
  __shared__ short hl[16 * 512];      // h lo plane
  const int tid = threadIdx.x, lane = tid & 63, wave = tid >> 6;
  const int team = blockIdx.x & 31, slice = blockIdx.x >> 5;
  const int b0 = team * 8;
  const int nc = slice * 64 + wave * 16;          // this wave's global col base

  // ---- prologue: Wh B-fragments into registers (hi+lo, 16 k-steps) ----
  short8 Bh[16], Bl[16];
  {
    const size_t col = (size_t)(nc + (lane & 15));
    const int kb = (lane >> 4) * 8;
    #pragma unroll
    for (int ks = 0; ks < 16; ++ks){
      Bh[ks] = *(const short8*)(WhTh + col * 512 + ks * 32 + kb);
      Bl[ks] = *(const short8*)(WhTl + col * 512 + ks * 32 + kb);
    }
    #pragma unroll
    for (int ks = 0; ks < 16; ++ks){
      asm volatile("" : "+v"(Bh[ks]), "+v"(Bl[ks]));
    }
  }
  // zero pad rows 8..15 once; fill rows 0..7 with init
  for (int v = tid; v < 8 * 512; v += 256){
    int r = 8 + (v >> 9), k = v & 511;
    hh[HIDX(r, k)] = 0; hl[HIDX(r, k)] = 0;
  }
  for (int v = tid; v < 8 * 512; v += 256){
    int r = v >> 9, k = v & 511;
    short hi, lo; split2(init[k], hi, lo);
    hh[HIDX(r, k)] = hi; hl[HIDX(r, k)] = lo;
  }
  __syncthreads();

  // ---- per-lane epilogue constants (same mapping as verified r2/r3/r4) ----
  const int cc = lane & 15;
  const bool islo = (lane < 32);
  const int mbase = ((lane & 31) >> 4) * 4;
  const int m_0 = mbase + (islo ? 0 : 2);
  const int m_1 = mbase + (islo ? 1 : 3);
  const int n = nc + cc;                           // global col of this lane
  float hr0 = init[n], hr1 = init[n];              // fp32 residual masters

  const int am = lane & 15, kb = (lane >> 4) * 8;
  const int rr = tid >> 5, c0 = (tid & 31) * 16;   // exchange-read assignment

  for (int t = 0; t < 256; ++t){
    // prefetch xproj for this lane's two elements (overlaps poll)
    const float* xpb = (t < 128) ? xp0 : xp1;
    const int tt = (t < 128) ? t : t - 128;
    const float xv0 = xpb[((size_t)tt * 256 + b0 + m_0) * 512 + n];
    const float xv1 = xpb[((size_t)tt * 256 + b0 + m_1) * 512 + n];

    if (t > 0){
      const unsigned tagv = (unsigned)t;
      // 1) poll this team's 8 flags (one 32B line, wave-uniform address)
      const unsigned* flg = flags + (((size_t)(t & 1)) * 32 + team) * 32;
      u32x4 f0, f1;
      while (true){
        asm volatile("global_load_dwordx4 %0, %1, off sc0 sc1" : "=&v"(f0) : "v"(flg)     : "memory");
        asm volatile("global_load_dwordx4 %0, %1, off sc0 sc1" : "=&v"(f1) : "v"(flg + 4) : "memory");
        asm volatile("s_waitcnt vmcnt(0)" : "+v"(f0), "+v"(f1) :: "memory");
        if (f0.x >= tagv && f0.y >= tagv && f0.z >= tagv && f0.w >= tagv &&
            f1.x >= tagv && f1.y >= tagv && f1.z >= tagv && f1.w >= tagv) break;
        __builtin_amdgcn_s_sleep(1);
      }
      // 2) bulk payload read: row rr, cols c0..c0+15 (64B), one vmcnt(0)
      const unsigned* src = pay + ((((size_t)(t & 1)) * 32 + team) * 8 + rr) * 512 + c0;
      u32x4 g0, g1, g2, g3;
      asm volatile("global_load_dwordx4 %0, %1, off sc0 sc1" : "=&v"(g0) : "v"(src +  0) : "memory");
      asm volatile("global_load_dwordx4 %0, %1, off sc0 sc1" : "=&v"(g1) : "v"(src +  4) : "memory");
      asm volatile("global_load_dwordx4 %0, %1, off sc0 sc1" : "=&v"(g2) : "v"(src +  8) : "memory");
      asm volatile("global_load_dwordx4 %0, %1, off sc0 sc1" : "=&v"(g3) : "v"(src + 12) : "memory");
      asm volatile("s_waitcnt vmcnt(0)"
                   : "+v"(g0), "+v"(g1), "+v"(g2), "+v"(g3) :: "memory");
      // 3) unpack -> LDS hi/lo planes
      short8 h0v, h1v, l0v, l1v;
      #pragma unroll
      for (int i = 0; i < 4; ++i){
        unsigned pa = (i < 2) ? ((i == 0) ? g0.x : g0.z) : ((i == 2) ? g1.x : g1.z);
        (void)pa;
      }
      // cols c0+0..3 = g0, c0+4..7 = g1, c0+8..11 = g2, c0+12..15 = g3
      h0v[0] = (short)(g0.x >> 16); h0v[1] = (short)(g0.y >> 16);
      h0v[2] = (short)(g0.z >> 16); h0v[3] = (short)(g0.w >> 16);
      h0v[4] = (short)(g1.x >> 16); h0v[5] = (short)(g1.y >> 16);
      h0v[6] = (short)(g1.z >> 16); h0v[7] = (short)(g1.w >> 16);
      h1v[0] = (short)(g2.x >> 16); h1v[1] = (short)(g2.y >> 16);
      h1v[2] = (short)(g2.z >> 16); h1v[3] = (short)(g2.w >> 16);
      h1v[4] = (short)(g3.x >> 16); h1v[5] = (short)(g3.y >> 16);
      h1v[6] = (short)(g3.z >> 16); h1v[7] = (short)(g3.w >> 16);
      l0v[0] = (short)(g0.x & 0xffffu); l0v[1] = (short)(g0.y & 0xffffu);
      l0v[2] = (short)(g0.z & 0xffffu); l0v[3] = (short)(g0.w & 0xffffu);
      l0v[4] = (short)(g1.x & 0xffffu); l0v[5] = (short)(g1.y & 0xffffu);
      l0v[6] = (short)(g1.z & 0xffffu); l0v[7] = (short)(g1.w & 0xffffu);
      l1v[0] = (short)(g2.x & 0xffffu); l1v[1] = (short)(g2.y & 0xffffu);
      l1v[2] = (short)(g2.z & 0xffffu); l1v[3] = (short)(g2.w & 0xffffu);
      l1v[4] = (short)(g3.x & 0xffffu); l1v[5] = (short)(g3.y & 0xffffu);
      l1v[6] = (short)(g3.z & 0xffffu); l1v[7] = (short)(g3.w & 0xffffu);
      *(short8*)&hh[HIDX(rr, c0)]     = h0v;
      *(short8*)&hh[HIDX(rr, c0 + 8)] = h1v;
      *(short8*)&hl[HIDX(rr, c0)]     = l0v;
      *(short8*)&hl[HIDX(rr, c0 + 8)] = l1v;
      __syncthreads();
    }

    // MFMA: 3 independent accumulator chains (hh, hl, lh)
    f32x4 ahh = {}, ahl = {}, alh = {};
    #pragma unroll
    for (int ks = 0; ks < 16; ++ks){
      short8 Ah = *(const short8*)&hh[HIDX(am, ks * 32 + kb)];
      short8 Al = *(const short8*)&hl[HIDX(am, ks * 32 + kb)];
      ahh = __builtin_amdgcn_mfma_f32_16x16x32_bf16(Ah, Bh[ks], ahh, 0, 0, 0);
      ahl = __builtin_amdgcn_mfma_f32_16x16x32_bf16(Ah, Bl[ks], ahl, 0, 0, 0);
      alh = __builtin_amdgcn_mfma_f32_16x16x32_bf16(Al, Bh[ks], alh, 0, 0, 0);
    }
    const float s0 = ahh[0] + (ahl[0] + alh[0]);
    const float s1 = ahh[1] + (ahl[1] + alh[1]);
    const float s2 = ahh[2] + (ahl[2] + alh[2]);
    const float s3 = ahh[3] + (ahl[3] + alh[3]);
    const float t2 = __shfl(s2, lane ^ 32);
    const float t3 = __shfl(s3, lane ^ 32);
    const float v0 = islo ? s0 : t2;
    const float v1 = islo ? s1 : t3;

    const float hn0 = tanh_fast(xv0 + v0) + hr0;
    const float hn1 = tanh_fast(xv1 + v1) + hr1;
    hr0 = hn0; hr1 = hn1;

    if (t < 255){
      // publish payload for h_{t+1} (parity (t+1)&1)
      unsigned* dst = pay + ((((size_t)((t + 1) & 1)) * 32 + team) * 8) * 512;
      unsigned w0 = pack2(hn0), w1 = pack2(hn1);
      unsigned* a0 = dst + (size_t)m_0 * 512 + n;
      unsigned* a1 = dst + (size_t)m_1 * 512 + n;
      asm volatile("global_store_dword %0, %1, off sc0 sc1" :: "v"(a0), "v"(w0) : "memory");
      asm volatile("global_store_dword %0, %1, off sc0 sc1" :: "v"(a1), "v"(w1) : "memory");
    }
    // states write (plain)
    states[((size_t)(b0 + m_0) * 256 + t) * 512 + n] = f2bf(hn0);
    states[((size_t)(b0 + m_1) * 256 + t) * 512 + n] = f2bf(hn1);

    if (t < 255){
      // drain own stores (payload ack'd at coherence point), then block
      // barrier, then leader posts the flag for step t+1.
      asm volatile("s_waitcnt vmcnt(0)" ::: "memory");
      __syncthreads();
      if (tid == 0){
        unsigned* fdst = flags + (((size_t)((t + 1) & 1)) * 32 + team) * 32 + slice;
        unsigned tagn = (unsigned)(t + 1);
        asm volatile("global_store_dword %0, %1, off sc0 sc1" :: "v"(fdst), "v"(tagn) : "memory");
      }
    }
  }
}

// ---------------------------------------------------------------------------
// K4: single-precision bf16 GEMM for the output projection (fp32 out).
// ---------------------------------------------------------------------------
__global__ __launch_bounds__(256) void gemm_bias_f32(
    const short* __restrict__ A, const short* __restrict__ Bt,
    const float* __restrict__ bias, float* __restrict__ C,
    int M, int N, int K)
{
  __shared__ short lA[64][72];
  __shared__ short lB[64][72];
  const int m0 = blockIdx.y * 64, n0 = blockIdx.x * 64;
  const int tid = threadIdx.x;
  const int lane = tid & 63, wave = tid >> 6;
  const int wm = (wave >> 1) * 32, wn = (wave & 1) * 32;
  f32x4 acc[2][2] = {};
  for (int k0 = 0; k0 < K; k0 += 64){
    __syncthreads();
    for (int v = tid; v < 512; v += 256){
      int r = v >> 3, c = v & 7;
      *(short8*)&lA[r][c*8] = *(const short8*)(A + (size_t)(m0 + r) * K + k0 + c*8);
      *(short8*)&lB[r][c*8] = *(const short8*)(Bt + (size_t)(n0 + r) * K + k0 + c*8);
    }
    __syncthreads();
    #pragma unroll
    for (int kk = 0; kk < 64; kk += 32){
      int ko = kk + (lane >> 4) * 8;
      short8 a0 = *(const short8*)&lA[wm +      (lane & 15)][ko];
      short8 a1 = *(const short8*)&lA[wm + 16 + (lane & 15)][ko];
      short8 b0 = *(const short8*)&lB[wn +      (lane & 15)][ko];
      short8 b1 = *(const short8*)&lB[wn + 16 + (lane & 15)][ko];
      acc[0][0] = __builtin_amdgcn_mfma_f32_16x16x32_bf16(a0, b0, acc[0][0], 0, 0, 0);
      acc[0][1] = __builtin_amdgcn_mfma_f32_16x16x32_bf16(a0, b1, acc[0][1], 0, 0, 0);
      acc[1][0] = __builtin_amdgcn_mfma_f32_16x16x32_bf16(a1, b0, acc[1][0], 0, 0, 0);
      acc[1][1] = __builtin_amdgcn_mfma_f32_16x16x32_bf16(a1, b1, acc[1][1], 0, 0, 0);
    }
  }
  const int cr = (lane >> 4) * 4, cc = lane & 15;
  #pragma unroll
  for (int i = 0; i < 2; ++i)
  #pragma unroll
  for (int j = 0; j < 2; ++j){
    int row = m0 + wm + i * 16 + cr;
    int col = n0 + wn + j * 16 + cc;
    float bv = bias[col];
    #pragma unroll
    for (int r = 0; r < 4; ++r){
      C[(size_t)(row + r) * N + col] = acc[i][j][r] + bv;
    }
  }
}

// ---------------------------------------------------------------------------
extern "C" void kernel_launch(void* const* d_in, const int* in_sizes, int n_in,
                              void* d_out, int out_size, void* d_ws, size_t ws_size,
                              hipStream_t stream){
  (void)in_sizes; (void)n_in; (void)out_size;
  const float* x    = (const float*)d_in[0];
  const float* Wx   = (const float*)d_in[1];
  const float* Wh   = (const float*)d_in[2];
  const float* bias = (const float*)d_in[3];
  const float* Wout = (const float*)d_in[4];
  const float* bout = (const float*)d_in[5];
  const float* init = (const float*)d_in[6];
  float* out = (float*)d_out;

  char* p = (char*)d_ws;
  // [0,64Mi): xT hi+lo during GEMM1, then states (written only by rnn).
  short* xTh    = (short*)(p);
  short* xTl    = (short*)(p + 33554432);
  short* states = (short*)(p);
  // xproj fp32: rows [0,32768) in ws, rows [32768,65536) in d_out (dead until GEMM2).
  float* xproj0 = (float*)(p + 67108864);     // 64 MiB
  float* xproj1 = (float*)d_out;              // 64 MiB
  short* WxTh   = (short*)(p + 134217728);    // 256 KiB
  short* WxTl   = (short*)(p + 134479872);    // 256 KiB
  short* WhTh   = (short*)(p + 134742016);    // 512 KiB
  short* WhTl   = (short*)(p + 135266304);    // 512 KiB
  short* WoutT  = (short*)(p + 135790592);    // 256 KiB
  unsigned* pay   = (unsigned*)(p + 136052736); // 1 MiB  [2][32][8][512] u32
  unsigned* flags = (unsigned*)(p + 137101312); // 8 KiB  [2][32][32] u32
  if (ws_size < 137109504u){
    fprintf(stderr, "kernel_launch: ws_size=%zu < 137109504 needed\n", ws_size);
  }

  // clear flags every launch (graph-capture-safe); payload needs no reset
  hipMemsetAsync(flags, 0, 8192, stream);

  transpose_split<<<(256*512 + 255)/256, 256, 0, stream>>>(Wx, WxTh, WxTl, 256, 512);
  transpose_split<<<(512*512 + 255)/256, 256, 0, stream>>>(Wh, WhTh, WhTl, 512, 512);
  transpose_to_bf16<<<(512*256 + 255)/256, 256, 0, stream>>>(Wout, WoutT, 512, 256);
  transpose_x_split<<<dim3(256, 4, 4), 256, 0, stream>>>(x, xTh, xTl);
  // xproj = xT @ Wx + b at ~fp32 precision (3-product split MFMA)
  gemm1_split<<<dim3(8, 1024), 256, 0, stream>>>(xTh, xTl, WxTh, WxTl, bias,
                                                 xproj0, xproj1, 65536, 512, 256);
  // recurrence: 32 teams x 8 slices, flag-gated exchange
  rnn_steps_v5<<<256, 256, 0, stream>>>(xproj0, xproj1, WhTh, WhTl, init,
                                        states, pay, flags);
  // out = states @ Wout + bout (single bf16 product)
  gemm_bias_f32<<<dim3(4, 1024), 256, 0, stream>>>(states, WoutT, bout, out, 65536, 256, 512);
}